// Round 4
// baseline (75.497 us; speedup 1.0000x reference)
//
#include <hip/hip_runtime.h>
#include <stdint.h>

#define N_DET    4096
#define MAX_DET  100
#define NTHREADS 1024
#define IOU_THR  0.5f

typedef unsigned long long u64;

// Explicit-rounding helpers: prevent -ffp-contract=fast from FMA-fusing and
// changing bits vs the JAX/NumPy reference (R1-R3 passed with absmax 0.0).
__device__ __forceinline__ float fadd(float a, float b) { return __fadd_rn(a, b); }
__device__ __forceinline__ float fsub(float a, float b) { return __fsub_rn(a, b); }
__device__ __forceinline__ float fmul(float a, float b) { return __fmul_rn(a, b); }

struct Box { float x1, y1, x2, y2; };

__device__ __forceinline__ Box decode_box(const float* __restrict__ box_b,
                                          const int*   __restrict__ idx_b,
                                          const float* __restrict__ anchors,
                                          int i, float sz0, float sz1)
{
    int ai = idx_b[i];
    float a0 = anchors[ai * 4 + 0];
    float a1 = anchors[ai * 4 + 1];
    float a2 = anchors[ai * 4 + 2];
    float a3 = anchors[ai * 4 + 3];
    float yc_a = fmul(fadd(a0, a2), 0.5f);
    float xc_a = fmul(fadd(a1, a3), 0.5f);
    float ha = fsub(a2, a0);
    float wa = fsub(a3, a1);
    float ty = box_b[i * 4 + 0];
    float tx = box_b[i * 4 + 1];
    float th = box_b[i * 4 + 2];
    float tw = box_b[i * 4 + 3];
    float we = fmul(expf(tw), wa);
    float he = fmul(expf(th), ha);
    float yc = fadd(fmul(ty, ha), yc_a);
    float xc = fadd(fmul(tx, wa), xc_a);
    Box r;
    r.x1 = fsub(xc, fmul(we, 0.5f));
    r.y1 = fsub(yc, fmul(he, 0.5f));
    r.x2 = fadd(xc, fmul(we, 0.5f));
    r.y2 = fadd(yc, fmul(he, 0.5f));
    r.x1 = fminf(fmaxf(r.x1, 0.f), sz0);
    r.y1 = fminf(fmaxf(r.y1, 0.f), sz1);
    r.x2 = fminf(fmaxf(r.x2, 0.f), sz0);
    r.y2 = fminf(fmaxf(r.y2, 0.f), sz1);
    return r;
}

__device__ __forceinline__ float sigmoidf_ref(float x)
{
    return __fdiv_rn(1.0f, __fadd_rn(1.0f, expf(-x)));
}

__device__ __forceinline__ bool iou_suppress(float hx1, float hy1, float hx2, float hy2, float har,
                                             float cx1, float cy1, float cx2, float cy2, float car)
{
    float lt0 = fmaxf(hx1, cx1);
    float lt1 = fmaxf(hy1, cy1);
    float rb0 = fminf(hx2, cx2);
    float rb1 = fminf(hy2, cy2);
    float w0 = fmaxf(fsub(rb0, lt0), 0.f);
    float w1 = fmaxf(fsub(rb1, lt1), 0.f);
    float inter = fmul(w0, w1);
    float uni = fsub(fadd(har, car), inter);
    float iou = __fdiv_rn(inter, fmaxf(uni, 1e-8f));
    return iou > IOU_THR;
}

// ---- bitonic helpers (register / shuffle, wave-local) ----
__device__ __forceinline__ u64 shfl_xor_u64(u64 x, int mask)
{
    unsigned lo = (unsigned)x, hi = (unsigned)(x >> 32);
    lo = __shfl_xor(lo, mask, 64);
    hi = __shfl_xor(hi, mask, 64);
    return ((u64)hi << 32) | lo;
}

__device__ __forceinline__ void cex(u64& a, u64& b, bool desc)
{
    bool sw = desc ? (a < b) : (a > b);
    u64 ta = a, tb = b;
    a = sw ? tb : ta;
    b = sw ? ta : tb;
}

__device__ __forceinline__ void shuf_pass(u64 e[4], int d, bool desc, int l)
{
    bool lower = ((l & d) == 0);
    bool keepmax = (desc == lower);
    #pragma unroll
    for (int s = 0; s < 4; ++s) {
        u64 p = shfl_xor_u64(e[s], d);
        u64 mx = (e[s] > p) ? e[s] : p;
        u64 mn = (e[s] < p) ? e[s] : p;
        e[s] = keepmax ? mx : mn;
    }
}

__global__ __launch_bounds__(NTHREADS, 1)
void effdet_nms_kernel(const float* __restrict__ cls_outputs,  // B,N,1
                       const float* __restrict__ box_outputs,  // B,N,4
                       const int*   __restrict__ indices,      // B,N
                       const int*   __restrict__ classes,      // B,N
                       const float* __restrict__ anchors,      // A,4
                       const float* __restrict__ img_scale,    // B
                       const float* __restrict__ img_size,     // B,2
                       float*       __restrict__ out)          // B,MAX_DET,6
{
    __shared__ u64    keys[N_DET];     // 32 KB: 16 sorted descending runs of 256
    __shared__ float4 sbx[N_DET];      // 64 KB: shifted x1,y1,x2,y2
    __shared__ float  sar[N_DET];      // 16 KB: shifted-box area
    __shared__ float  warp_red_f[16];
    __shared__ int    sel[MAX_DET];

    const int b = blockIdx.x;
    const int t = threadIdx.x;
    const int l = t & 63;              // lane

    const float* cls_b    = cls_outputs + (size_t)b * N_DET;
    const float* box_b    = box_outputs + (size_t)b * N_DET * 4;
    const int*   idx_b    = indices + (size_t)b * N_DET;
    const int*   cls_id_b = classes + (size_t)b * N_DET;
    const float  scale    = img_scale[b];
    const float  sz0      = __fdiv_rn(img_size[b * 2 + 0], scale);
    const float  sz1      = __fdiv_rn(img_size[b * 2 + 1], scale);

    // ---------- Pass 1: decode 4 consecutive elements/thread; keys; block max ----------
    // Thread t owns elements 4t..4t+3; wave w owns the contiguous run [256w, 256w+256).
    u64 e[4];
    Box bx[4];
    float lmax = 0.0f;                 // coords >= 0 after clamp
    const int4   idx4 = ((const int4*)idx_b)[t];        // vectorized aux loads
    const float4 cl4  = ((const float4*)cls_b)[t];
    const int4   cid4 = ((const int4*)cls_id_b)[t];
    const int idxs[4] = { idx4.x, idx4.y, idx4.z, idx4.w };
    const float cls4[4] = { cl4.x, cl4.y, cl4.z, cl4.w };
    const int cids[4] = { cid4.x, cid4.y, cid4.z, cid4.w };
    #pragma unroll
    for (int s = 0; s < 4; ++s) {
        int i = 4 * t + s;
        // inline decode using preloaded idx (identical arithmetic to decode_box)
        int ai = idxs[s];
        float a0 = anchors[ai * 4 + 0];
        float a1 = anchors[ai * 4 + 1];
        float a2 = anchors[ai * 4 + 2];
        float a3 = anchors[ai * 4 + 3];
        float yc_a = fmul(fadd(a0, a2), 0.5f);
        float xc_a = fmul(fadd(a1, a3), 0.5f);
        float ha = fsub(a2, a0);
        float wa = fsub(a3, a1);
        float ty = box_b[i * 4 + 0];
        float tx = box_b[i * 4 + 1];
        float th = box_b[i * 4 + 2];
        float tw = box_b[i * 4 + 3];
        float we = fmul(expf(tw), wa);
        float he = fmul(expf(th), ha);
        float yc = fadd(fmul(ty, ha), yc_a);
        float xc = fadd(fmul(tx, wa), xc_a);
        Box r;
        r.x1 = fsub(xc, fmul(we, 0.5f));
        r.y1 = fsub(yc, fmul(he, 0.5f));
        r.x2 = fadd(xc, fmul(we, 0.5f));
        r.y2 = fadd(yc, fmul(he, 0.5f));
        r.x1 = fminf(fmaxf(r.x1, 0.f), sz0);
        r.y1 = fminf(fmaxf(r.y1, 0.f), sz1);
        r.x2 = fminf(fmaxf(r.x2, 0.f), sz0);
        r.y2 = fminf(fmaxf(r.y2, 0.f), sz1);
        bx[s] = r;
        lmax = fmaxf(lmax, fmaxf(fmaxf(r.x1, r.y1), fmaxf(r.x2, r.y2)));
        float sc = sigmoidf_ref(cls4[s]);
        e[s] = ((u64)__float_as_uint(sc) << 32) | (unsigned)(N_DET - 1 - i);
    }
    for (int o = 32; o; o >>= 1) lmax = fmaxf(lmax, __shfl_xor(lmax, o, 64));
    if (l == 0) warp_red_f[t >> 6] = lmax;
    __syncthreads();   // barrier #1: publish wave maxima

    // ---------- M, then shifted boxes + areas into LDS ----------
    float mm = warp_red_f[0];
    #pragma unroll
    for (int k = 1; k < 16; ++k) mm = fmaxf(mm, warp_red_f[k]);
    const float M = fadd(mm, 1.0f);    // jnp.max(b) + 1.0

    #pragma unroll
    for (int s = 0; s < 4; ++s) {
        int i = 4 * t + s;
        float off = fmul((float)cids[s], M);   // c.astype(f32) * (max+1)
        float x1 = fadd(bx[s].x1, off), y1 = fadd(bx[s].y1, off);
        float x2 = fadd(bx[s].x2, off), y2 = fadd(bx[s].y2, off);
        sbx[i] = make_float4(x1, y1, x2, y2);
        sar[i] = fmul(fmaxf(fsub(x2, x1), 0.f), fmaxf(fsub(y2, y1), 0.f));
    }

    // ---------- Wave-local bitonic sort: 256 elements descending, registers only ----------
    // Local index il = 4*l + s; direction rule desc <=> (il & k) == 0; k=256 => true.
    cex(e[0], e[1], true);
    cex(e[2], e[3], false);
    for (int k = 4; k <= 128; k <<= 1) {
        bool desc = (l & (k >> 2)) == 0;
        for (int j = k >> 1; j >= 4; j >>= 1) shuf_pass(e, j >> 2, desc, l);
        cex(e[0], e[2], desc); cex(e[1], e[3], desc);
        cex(e[0], e[1], desc); cex(e[2], e[3], desc);
    }
    {   // k = 256: whole-run merge, descending
        const bool desc = true;
        for (int j = 128; j >= 4; j >>= 1) shuf_pass(e, j >> 2, desc, l);
        cex(e[0], e[2], desc); cex(e[1], e[3], desc);
        cex(e[0], e[1], desc); cex(e[2], e[3], desc);
    }
    #pragma unroll
    for (int s = 0; s < 4; ++s) keys[4 * t + s] = e[s];
    __syncthreads();   // barrier #2: runs + shifted boxes visible to scan wave

    // ---------- Single-wave 16-way merge + greedy scan (exact reference order) ----------
    if (t >= 64) return;
    const int lane = t;

    for (int r = lane; r < MAX_DET; r += 64) sel[r] = -1;

    // merge state: lane i<16 owns run i with 2-deep prefetch
    u64 cur = 0, nxt = 0;
    int ptr = 2;
    if (lane < 16) {
        cur = keys[lane * 256 + 0];
        nxt = keys[lane * 256 + 1];
    }

    // heads: slot0 = head #lane, slot1 = head #(lane+64)
    float h0x1 = 0, h0y1 = 0, h0x2 = 0, h0y2 = 0, h0ar = 0;
    float h1x1 = 0, h1y1 = 0, h1x2 = 0, h1y2 = 0, h1ar = 0;
    bool have0 = false, have1 = false;
    int count = 0;

    for (int c = 0; c < N_DET && count < MAX_DET; ++c) {
        // winner = max key among lanes 0..15 (keys are distinct)
        u64 w = (lane < 16) ? cur : 0;
        #pragma unroll
        for (int d = 1; d <= 8; d <<= 1) {
            u64 ok = shfl_xor_u64(w, d);
            if (ok > w) w = ok;
        }
        unsigned wlo = __builtin_amdgcn_readfirstlane((unsigned)w);
        unsigned whi = __builtin_amdgcn_readfirstlane((unsigned)(w >> 32));
        u64 wkey = ((u64)whi << 32) | wlo;
        if (wkey == 0) break;                       // all runs exhausted
        unsigned long long mask = __ballot((lane < 16) && (cur == wkey));
        int wlane = __ffsll(mask) - 1;
        int orig = N_DET - 1 - (int)(unsigned)(wkey & 0xFFFFFFFFull);

        // winner lane advances its run (prefetch hides LDS latency)
        if (lane == wlane) {
            cur = nxt;
            nxt = (ptr < 256) ? keys[lane * 256 + ptr] : 0;
            ++ptr;
        }

        // candidate shifted box + area: LDS broadcast reads
        float4 c4 = sbx[orig];
        float car = sar[orig];

        bool sup = false;
        if (have0) sup = iou_suppress(h0x1, h0y1, h0x2, h0y2, h0ar, c4.x, c4.y, c4.z, c4.w, car);
        if (have1) sup = sup || iou_suppress(h1x1, h1y1, h1x2, h1y2, h1ar, c4.x, c4.y, c4.z, c4.w, car);

        if (!__any(sup ? 1 : 0)) {
            if (count < 64) {
                if (lane == count) {
                    h0x1 = c4.x; h0y1 = c4.y; h0x2 = c4.z; h0y2 = c4.w; h0ar = car;
                    have0 = true;
                }
            } else {
                if (lane == count - 64) {
                    h1x1 = c4.x; h1y1 = c4.y; h1x2 = c4.z; h1y2 = c4.w; h1ar = car;
                    have1 = true;
                }
            }
            if (lane == 0) sel[count] = orig;
            ++count;
        }
    }

    // ---------- Emit output rows (re-decode <=100 boxes; validated exact path) ----------
    for (int r = lane; r < MAX_DET; r += 64) {
        int sidx = sel[r];
        float* o = out + (size_t)b * MAX_DET * 6 + (size_t)r * 6;
        if (sidx < 0) {
            o[0] = 0.f; o[1] = 0.f; o[2] = 0.f; o[3] = 0.f; o[4] = 0.f; o[5] = 0.f;
        } else {
            Box bb = decode_box(box_b, idx_b, anchors, sidx, sz0, sz1);
            float sc = sigmoidf_ref(cls_b[sidx]);
            int c = cls_id_b[sidx];
            o[0] = fmul(bb.x1, scale);
            o[1] = fmul(bb.y1, scale);
            o[2] = fmul(bb.x2, scale);
            o[3] = fmul(bb.y2, scale);
            o[4] = sc;
            o[5] = (float)(c + 1);
        }
    }
}

extern "C" void kernel_launch(void* const* d_in, const int* in_sizes, int n_in,
                              void* d_out, int out_size, void* d_ws, size_t ws_size,
                              hipStream_t stream)
{
    const float* cls_outputs = (const float*)d_in[0];
    const float* box_outputs = (const float*)d_in[1];
    const int*   indices     = (const int*)d_in[2];
    const int*   classes     = (const int*)d_in[3];
    const float* anchors     = (const float*)d_in[4];
    const float* img_scale   = (const float*)d_in[5];
    const float* img_size    = (const float*)d_in[6];
    float*       out         = (float*)d_out;

    const int B = in_sizes[5];   // img_scale has B elements

    effdet_nms_kernel<<<dim3(B), dim3(NTHREADS), 0, stream>>>(
        cls_outputs, box_outputs, indices, classes, anchors,
        img_scale, img_size, out);
}

// Round 5
// 67.233 us; speedup vs baseline: 1.1229x; 1.1229x over previous
//
#include <hip/hip_runtime.h>
#include <stdint.h>

#define N_DET    4096
#define MAX_DET  100
#define NTHREADS 1024
#define IOU_THR  0.5f

typedef unsigned long long u64;

// Explicit-rounding helpers: prevent -ffp-contract=fast from FMA-fusing and
// changing bits vs the JAX/NumPy reference (R1-R4 all passed with absmax 0.0).
__device__ __forceinline__ float fadd(float a, float b) { return __fadd_rn(a, b); }
__device__ __forceinline__ float fsub(float a, float b) { return __fsub_rn(a, b); }
__device__ __forceinline__ float fmul(float a, float b) { return __fmul_rn(a, b); }

struct Box { float x1, y1, x2, y2; };

__device__ __forceinline__ Box decode_box(const float* __restrict__ box_b,
                                          const int*   __restrict__ idx_b,
                                          const float* __restrict__ anchors,
                                          int i, float sz0, float sz1)
{
    int ai = idx_b[i];
    float a0 = anchors[ai * 4 + 0];
    float a1 = anchors[ai * 4 + 1];
    float a2 = anchors[ai * 4 + 2];
    float a3 = anchors[ai * 4 + 3];
    float yc_a = fmul(fadd(a0, a2), 0.5f);
    float xc_a = fmul(fadd(a1, a3), 0.5f);
    float ha = fsub(a2, a0);
    float wa = fsub(a3, a1);
    float ty = box_b[i * 4 + 0];
    float tx = box_b[i * 4 + 1];
    float th = box_b[i * 4 + 2];
    float tw = box_b[i * 4 + 3];
    float we = fmul(expf(tw), wa);
    float he = fmul(expf(th), ha);
    float yc = fadd(fmul(ty, ha), yc_a);
    float xc = fadd(fmul(tx, wa), xc_a);
    Box r;
    r.x1 = fsub(xc, fmul(we, 0.5f));
    r.y1 = fsub(yc, fmul(he, 0.5f));
    r.x2 = fadd(xc, fmul(we, 0.5f));
    r.y2 = fadd(yc, fmul(he, 0.5f));
    r.x1 = fminf(fmaxf(r.x1, 0.f), sz0);
    r.y1 = fminf(fmaxf(r.y1, 0.f), sz1);
    r.x2 = fminf(fmaxf(r.x2, 0.f), sz0);
    r.y2 = fminf(fmaxf(r.y2, 0.f), sz1);
    return r;
}

__device__ __forceinline__ float sigmoidf_ref(float x)
{
    return __fdiv_rn(1.0f, __fadd_rn(1.0f, expf(-x)));
}

// head (earlier-selected) first: union = area[head] + area[cand] - inter
__device__ __forceinline__ bool iou_suppress(float hx1, float hy1, float hx2, float hy2, float har,
                                             float cx1, float cy1, float cx2, float cy2, float car)
{
    float lt0 = fmaxf(hx1, cx1);
    float lt1 = fmaxf(hy1, cy1);
    float rb0 = fminf(hx2, cx2);
    float rb1 = fminf(hy2, cy2);
    float w0 = fmaxf(fsub(rb0, lt0), 0.f);
    float w1 = fmaxf(fsub(rb1, lt1), 0.f);
    float inter = fmul(w0, w1);
    float uni = fsub(fadd(har, car), inter);
    float iou = __fdiv_rn(inter, fmaxf(uni, 1e-8f));
    return iou > IOU_THR;
}

// ---- bitonic helpers (register / shuffle) ----
__device__ __forceinline__ u64 shfl_xor_u64(u64 x, int mask)
{
    unsigned lo = (unsigned)x, hi = (unsigned)(x >> 32);
    lo = __shfl_xor(lo, mask, 64);
    hi = __shfl_xor(hi, mask, 64);
    return ((u64)hi << 32) | lo;
}

__device__ __forceinline__ void cex(u64& a, u64& b, bool desc)
{
    bool sw = desc ? (a < b) : (a > b);
    u64 ta = a, tb = b;
    a = sw ? tb : ta;
    b = sw ? ta : tb;
}

__device__ __forceinline__ void shuf_pass(u64 e[4], int d, bool desc, int l)
{
    bool lower = ((l & d) == 0);
    bool keepmax = (desc == lower);
    #pragma unroll
    for (int s = 0; s < 4; ++s) {
        u64 p = shfl_xor_u64(e[s], d);
        u64 mx = (e[s] > p) ? e[s] : p;
        u64 mn = (e[s] < p) ? e[s] : p;
        e[s] = keepmax ? mx : mn;
    }
}

__global__ __launch_bounds__(NTHREADS, 1)
void effdet_nms_kernel(const float* __restrict__ cls_outputs,  // B,N,1
                       const float* __restrict__ box_outputs,  // B,N,4
                       const int*   __restrict__ indices,      // B,N
                       const int*   __restrict__ classes,      // B,N
                       const float* __restrict__ anchors,      // A,4
                       const float* __restrict__ img_scale,    // B
                       const float* __restrict__ img_size,     // B,2
                       float*       __restrict__ out)          // B,MAX_DET,6
{
    __shared__ u64    keys[N_DET];     // 32 KB, globally sorted descending after phase B
    __shared__ float4 sbx[N_DET];      // 64 KB: shifted x1,y1,x2,y2 (by orig index)
    __shared__ float  sar[N_DET];      // 16 KB: shifted-box area
    __shared__ float  warp_red_f[16];
    __shared__ int    sel[MAX_DET];
    __shared__ float  hdx1[MAX_DET], hdy1[MAX_DET], hdx2[MAX_DET], hdy2[MAX_DET], hdar[MAX_DET];

    const int b = blockIdx.x;
    const int t = threadIdx.x;
    const int l = t & 63;              // lane

    const float* cls_b    = cls_outputs + (size_t)b * N_DET;
    const float* box_b    = box_outputs + (size_t)b * N_DET * 4;
    const int*   idx_b    = indices + (size_t)b * N_DET;
    const int*   cls_id_b = classes + (size_t)b * N_DET;
    const float  scale    = img_scale[b];
    const float  sz0      = __fdiv_rn(img_size[b * 2 + 0], scale);
    const float  sz1      = __fdiv_rn(img_size[b * 2 + 1], scale);

    // ---------- Pass 1: decode 4 consecutive elements/thread; keys; block max ----------
    u64 e[4];
    Box bx[4];
    float lmax = 0.0f;                 // coords >= 0 after clamp
    const int4   idx4 = ((const int4*)idx_b)[t];
    const float4 cl4  = ((const float4*)cls_b)[t];
    const int4   cid4 = ((const int4*)cls_id_b)[t];
    const int   idxs[4] = { idx4.x, idx4.y, idx4.z, idx4.w };
    const float cls4[4] = { cl4.x, cl4.y, cl4.z, cl4.w };
    const int   cids[4] = { cid4.x, cid4.y, cid4.z, cid4.w };
    #pragma unroll
    for (int s = 0; s < 4; ++s) {
        int i = 4 * t + s;
        int ai = idxs[s];
        float a0 = anchors[ai * 4 + 0];
        float a1 = anchors[ai * 4 + 1];
        float a2 = anchors[ai * 4 + 2];
        float a3 = anchors[ai * 4 + 3];
        float yc_a = fmul(fadd(a0, a2), 0.5f);
        float xc_a = fmul(fadd(a1, a3), 0.5f);
        float ha = fsub(a2, a0);
        float wa = fsub(a3, a1);
        float ty = box_b[i * 4 + 0];
        float tx = box_b[i * 4 + 1];
        float th = box_b[i * 4 + 2];
        float tw = box_b[i * 4 + 3];
        float we = fmul(expf(tw), wa);
        float he = fmul(expf(th), ha);
        float yc = fadd(fmul(ty, ha), yc_a);
        float xc = fadd(fmul(tx, wa), xc_a);
        Box r;
        r.x1 = fsub(xc, fmul(we, 0.5f));
        r.y1 = fsub(yc, fmul(he, 0.5f));
        r.x2 = fadd(xc, fmul(we, 0.5f));
        r.y2 = fadd(yc, fmul(he, 0.5f));
        r.x1 = fminf(fmaxf(r.x1, 0.f), sz0);
        r.y1 = fminf(fmaxf(r.y1, 0.f), sz1);
        r.x2 = fminf(fmaxf(r.x2, 0.f), sz0);
        r.y2 = fminf(fmaxf(r.y2, 0.f), sz1);
        bx[s] = r;
        lmax = fmaxf(lmax, fmaxf(fmaxf(r.x1, r.y1), fmaxf(r.x2, r.y2)));
        float sc = sigmoidf_ref(cls4[s]);
        e[s] = ((u64)__float_as_uint(sc) << 32) | (unsigned)(N_DET - 1 - i);
    }
    for (int o = 32; o; o >>= 1) lmax = fmaxf(lmax, __shfl_xor(lmax, o, 64));
    if (l == 0) warp_red_f[t >> 6] = lmax;
    __syncthreads();   // barrier #1: wave maxima visible

    // ---------- M; shifted boxes + areas into LDS; wave-local bitonic (k=2..256) ----------
    float mm = warp_red_f[0];
    #pragma unroll
    for (int k = 1; k < 16; ++k) mm = fmaxf(mm, warp_red_f[k]);
    const float M = fadd(mm, 1.0f);    // jnp.max(b) + 1.0

    #pragma unroll
    for (int s = 0; s < 4; ++s) {
        int i = 4 * t + s;
        float off = fmul((float)cids[s], M);   // c.astype(f32) * (max+1)
        float x1 = fadd(bx[s].x1, off), y1 = fadd(bx[s].y1, off);
        float x2 = fadd(bx[s].x2, off), y2 = fadd(bx[s].y2, off);
        sbx[i] = make_float4(x1, y1, x2, y2);
        sar[i] = fmul(fmaxf(fsub(x2, x1), 0.f), fmaxf(fsub(y2, y1), 0.f));
    }

    // Phase A (validated R3): global rule desc <=> ((4t+s) & k) == 0
    cex(e[0], e[1], true);
    cex(e[2], e[3], false);
    for (int k = 4; k <= 128; k <<= 1) {
        bool desc = (l & (k >> 2)) == 0;
        for (int j = k >> 1; j >= 4; j >>= 1) shuf_pass(e, j >> 2, desc, l);
        cex(e[0], e[2], desc); cex(e[1], e[3], desc);
        cex(e[0], e[1], desc); cex(e[2], e[3], desc);
    }
    {   // k = 256
        bool desc = ((t >> 6) & 1) == 0;
        for (int j = 128; j >= 4; j >>= 1) shuf_pass(e, j >> 2, desc, l);
        cex(e[0], e[2], desc); cex(e[1], e[3], desc);
        cex(e[0], e[1], desc); cex(e[2], e[3], desc);
    }
    #pragma unroll
    for (int s = 0; s < 4; ++s) keys[4 * t + s] = e[s];

    // ---------- Phase B (validated R3): cross-wave merges k = 512..4096 ----------
    for (int k = 512; k <= N_DET; k <<= 1) {
        for (int j = k >> 1; j >= 256; j >>= 1) {
            __syncthreads();
            #pragma unroll
            for (int vv = 0; vv < 2; ++vv) {
                int v = t + vv * NTHREADS;
                int i   = ((v & ~(j - 1)) << 1) | (v & (j - 1));
                int ixj = i | j;
                bool desc = ((i & k) == 0);
                u64 a = keys[i], c = keys[ixj];
                bool sw = desc ? (a < c) : (a > c);
                if (sw) { keys[i] = c; keys[ixj] = a; }
            }
        }
        __syncthreads();
        u64 f[4];
        #pragma unroll
        for (int s = 0; s < 4; ++s) f[s] = keys[4 * t + s];
        bool desc = (t & (k >> 2)) == 0;
        for (int j = 128; j >= 4; j >>= 1) shuf_pass(f, j >> 2, desc, l);
        cex(f[0], f[2], desc); cex(f[1], f[3], desc);
        cex(f[0], f[1], desc); cex(f[2], f[3], desc);
        #pragma unroll
        for (int s = 0; s < 4; ++s) keys[4 * t + s] = f[s];
    }
    __syncthreads();   // final barrier: sorted keys + sbx/sar visible

    // ---------- Single-wave batch-parallel greedy scan (exact reference order) ----------
    if (t >= 64) return;
    const int lane = t;

    for (int r = lane; r < MAX_DET; r += 64) sel[r] = -1;

    int count = 0;
    for (int c = 0; c < N_DET && count < MAX_DET; c += 64) {
        // lane j <- sorted candidate c+j
        int  pos  = c + lane;
        bool oob  = (pos >= N_DET);
        u64  key  = keys[oob ? (N_DET - 1) : pos];
        int  orig = N_DET - 1 - (int)(unsigned)(key & 0xFFFFFFFFull);
        float4 c4 = sbx[orig];
        float car = sar[orig];

        // ext-suppression vs all previously selected heads (broadcast reads, pipelinable)
        bool sup = oob;
        for (int k = 0; k < count; ++k) {
            sup = sup || iou_suppress(hdx1[k], hdy1[k], hdx2[k], hdy2[k], hdar[k],
                                      c4.x, c4.y, c4.z, c4.w, car);
        }
        u64 ext = __ballot(sup ? 1 : 0);

        // intra-batch pair matrix: C[j] = bits q>j with IoU(j,q) > thr (j as head)
        u64 C = 0;
        for (int r = 1; r < 64; ++r) {
            int q = (lane + r) & 63;
            float qx1 = __shfl(c4.x, q, 64);
            float qy1 = __shfl(c4.y, q, 64);
            float qx2 = __shfl(c4.z, q, 64);
            float qy2 = __shfl(c4.w, q, 64);
            float qar = __shfl(car,  q, 64);
            bool hit = (q > lane) && !oob && (c + q < N_DET) &&
                       iou_suppress(c4.x, c4.y, c4.z, c4.w, car,
                                    qx1, qy1, qx2, qy2, qar);
            C |= ((u64)(hit ? 1 : 0)) << q;
        }
        u64 hasC = __ballot(C != 0ull);

        // exact greedy closure over the 64-bit alive mask (wave-uniform scalar)
        u64 alive = ~ext;
        u64 selmask = 0;
        int total = count;
        while (alive && total < MAX_DET) {
            int k = __ffsll(alive) - 1;
            selmask |= (1ull << k);
            alive &= ~(1ull << k);
            ++total;
            if ((hasC >> k) & 1ull) {
                unsigned clo = __shfl((int)(unsigned)C, k, 64);
                unsigned chi = __shfl((int)(unsigned)(C >> 32), k, 64);
                alive &= ~(((u64)chi << 32) | clo);
            }
        }

        // append selected candidates as heads (parallel LDS scatter)
        if ((selmask >> lane) & 1ull) {
            int p = count + __popcll(selmask & ((1ull << lane) - 1ull));
            hdx1[p] = c4.x; hdy1[p] = c4.y; hdx2[p] = c4.z; hdy2[p] = c4.w; hdar[p] = car;
            sel[p] = orig;
        }
        count = total;
    }

    // ---------- Emit output rows (re-decode <=100 boxes; validated exact path) ----------
    for (int r = lane; r < MAX_DET; r += 64) {
        int sidx = sel[r];
        float* o = out + (size_t)b * MAX_DET * 6 + (size_t)r * 6;
        if (sidx < 0) {
            o[0] = 0.f; o[1] = 0.f; o[2] = 0.f; o[3] = 0.f; o[4] = 0.f; o[5] = 0.f;
        } else {
            Box bb = decode_box(box_b, idx_b, anchors, sidx, sz0, sz1);
            float sc = sigmoidf_ref(cls_b[sidx]);
            int c = cls_id_b[sidx];
            o[0] = fmul(bb.x1, scale);
            o[1] = fmul(bb.y1, scale);
            o[2] = fmul(bb.x2, scale);
            o[3] = fmul(bb.y2, scale);
            o[4] = sc;
            o[5] = (float)(c + 1);
        }
    }
}

extern "C" void kernel_launch(void* const* d_in, const int* in_sizes, int n_in,
                              void* d_out, int out_size, void* d_ws, size_t ws_size,
                              hipStream_t stream)
{
    const float* cls_outputs = (const float*)d_in[0];
    const float* box_outputs = (const float*)d_in[1];
    const int*   indices     = (const int*)d_in[2];
    const int*   classes     = (const int*)d_in[3];
    const float* anchors     = (const float*)d_in[4];
    const float* img_scale   = (const float*)d_in[5];
    const float* img_size    = (const float*)d_in[6];
    float*       out         = (float*)d_out;

    const int B = in_sizes[5];   // img_scale has B elements

    effdet_nms_kernel<<<dim3(B), dim3(NTHREADS), 0, stream>>>(
        cls_outputs, box_outputs, indices, classes, anchors,
        img_scale, img_size, out);
}